// Round 1
// baseline (1444.028 us; speedup 1.0000x reference)
//
#include <hip/hip_runtime.h>
#include <hip/hip_bf16.h>
#include <math.h>

#define S_ 2048

// ---------------- bias table: bias[h][rel + 2047], rel = k - q ----------------
__global__ void bias_table_kernel(const float* __restrict__ table,
                                  float* __restrict__ biasTab) {
  int idx = blockIdx.x * blockDim.x + threadIdx.x;
  if (idx >= 16 * 4096) return;
  int h = idx >> 12;
  int r = idx & 4095;
  int rel = r - 2047;                  // mem - ctx
  int bucket = rel > 0 ? 16 : 0;
  int ar = rel < 0 ? -rel : rel;
  if (ar < 8) {
    bucket += ar;
  } else {
    // mirror JAX fp32 arithmetic: log(ar/8) / log(16) * 8, truncate
    float tmp = logf((float)ar / 8.0f);
    float lf = tmp / 2.7725887222397811f * 8.0f;
    int large = 8 + (int)lf;
    bucket += (large < 15 ? large : 15);
  }
  biasTab[idx] = table[h * 32 + bucket];
}

// ---------------- fp32 GEMM + bias: C[M,N] = A[M,K] @ B[K,N] + bias[N] --------
__global__ __launch_bounds__(256) void gemm_bias_kernel(
    const float* __restrict__ A, const float* __restrict__ Bm,
    const float* __restrict__ bias, float* __restrict__ C,
    int M, int N, int K) {
  __shared__ __align__(16) float As[8][128];
  __shared__ __align__(16) float Bs[8][128];
  const int tid = threadIdx.x;
  const int m0 = blockIdx.y * 128, n0 = blockIdx.x * 128;
  const int ar = tid >> 1, ak = (tid & 1) * 4;
  const int bk = tid >> 5, bn = (tid & 31) * 4;
  const int tm = (tid >> 4) * 8, tn = (tid & 15) * 8;
  float acc[8][8] = {};
  const float* Aptr = A + (size_t)(m0 + ar) * K + ak;
  const float* Bptr = Bm + (size_t)bk * N + n0 + bn;

  for (int kt = 0; kt < K; kt += 8) {
    float4 av = *(const float4*)(Aptr + kt);
    float4 bv = *(const float4*)(Bptr + (size_t)kt * N);
    As[ak + 0][ar] = av.x;
    As[ak + 1][ar] = av.y;
    As[ak + 2][ar] = av.z;
    As[ak + 3][ar] = av.w;
    *(float4*)&Bs[bk][bn] = bv;
    __syncthreads();
#pragma unroll
    for (int kk = 0; kk < 8; ++kk) {
      float4 a0 = *(float4*)&As[kk][tm];
      float4 a1 = *(float4*)&As[kk][tm + 4];
      float4 b0 = *(float4*)&Bs[kk][tn];
      float4 b1 = *(float4*)&Bs[kk][tn + 4];
      float a[8] = {a0.x, a0.y, a0.z, a0.w, a1.x, a1.y, a1.z, a1.w};
      float bb[8] = {b0.x, b0.y, b0.z, b0.w, b1.x, b1.y, b1.z, b1.w};
#pragma unroll
      for (int i = 0; i < 8; ++i)
#pragma unroll
        for (int j = 0; j < 8; ++j)
          acc[i][j] += a[i] * bb[j];
    }
    __syncthreads();
  }
  float bcol[8];
#pragma unroll
  for (int j = 0; j < 8; ++j) bcol[j] = bias[n0 + tn + j];
#pragma unroll
  for (int i = 0; i < 8; ++i) {
    float4 o0, o1;
    o0.x = acc[i][0] + bcol[0]; o0.y = acc[i][1] + bcol[1];
    o0.z = acc[i][2] + bcol[2]; o0.w = acc[i][3] + bcol[3];
    o1.x = acc[i][4] + bcol[4]; o1.y = acc[i][5] + bcol[5];
    o1.z = acc[i][6] + bcol[6]; o1.w = acc[i][7] + bcol[7];
    float* crow = C + (size_t)(m0 + tm + i) * N + n0 + tn;
    *(float4*)crow = o0;
    *(float4*)(crow + 4) = o1;
  }
}

// ---------------- flash attention fp32, Q-tile 32, K-tile 64 ----------------
// grid: (64 qtiles, 16 heads, 2 batch), block 256
__global__ __launch_bounds__(256) void attn_kernel(
    const float* __restrict__ qkv, const float* __restrict__ biasTab,
    float* __restrict__ ctx) {
  const int qt = blockIdx.x;
  const int h = blockIdx.y;
  const int b = blockIdx.z;
  const int tid = threadIdx.x;

  __shared__ __align__(16) float Qs[32][68];
  __shared__ __align__(16) float Ks[64][68];
  __shared__ __align__(16) float Vs[64][68];
  __shared__ __align__(16) float Sc[32][68];
  __shared__ float mrow[32], lrow[32], scl[32];
  __shared__ float red[32][8];

  const int q0 = qt * 32;
  const float* qbase = qkv + (size_t)(b * S_ + q0) * 3072 + h * 64;

  // load Q tile (32x64) = 512 float4
  for (int i = tid; i < 512; i += 256) {
    int r = i >> 4, c = (i & 15) * 4;
    *(float4*)&Qs[r][c] = *(const float4*)&qbase[(size_t)r * 3072 + c];
  }
  if (tid < 32) { mrow[tid] = -1e30f; lrow[tid] = 0.f; }

  const int tq = (tid >> 4) * 2;   // 2 score rows
  const int tk = (tid & 15) * 4;   // 4 score cols / 4 out dims
  float acc[2][4] = {};

  const float* kbase = qkv + (size_t)b * S_ * 3072 + 1024 + h * 64;
  const float* vbase = qkv + (size_t)b * S_ * 3072 + 2048 + h * 64;
  const float* btab = biasTab + h * 4096 + 2047;

  for (int kt = 0; kt < 32; ++kt) {
    __syncthreads();   // previous iteration's reads of Ks/Vs/Sc complete
    for (int i = tid; i < 1024; i += 256) {
      int r = i >> 4, c = (i & 15) * 4;
      size_t off = (size_t)(kt * 64 + r) * 3072 + c;
      *(float4*)&Ks[r][c] = *(const float4*)&kbase[off];
      *(float4*)&Vs[r][c] = *(const float4*)&vbase[off];
    }
    __syncthreads();

    // ---- scores: s[2][4] = Q-rows(tq..tq+1) . K-rows(tk..tk+3) ----
    float s[2][4] = {};
    for (int d = 0; d < 64; d += 4) {
      float4 a0 = *(float4*)&Qs[tq][d];
      float4 a1 = *(float4*)&Qs[tq + 1][d];
      float4 k0 = *(float4*)&Ks[tk][d];
      float4 k1 = *(float4*)&Ks[tk + 1][d];
      float4 k2 = *(float4*)&Ks[tk + 2][d];
      float4 k3 = *(float4*)&Ks[tk + 3][d];
      s[0][0] += a0.x*k0.x + a0.y*k0.y + a0.z*k0.z + a0.w*k0.w;
      s[0][1] += a0.x*k1.x + a0.y*k1.y + a0.z*k1.z + a0.w*k1.w;
      s[0][2] += a0.x*k2.x + a0.y*k2.y + a0.z*k2.z + a0.w*k2.w;
      s[0][3] += a0.x*k3.x + a0.y*k3.y + a0.z*k3.z + a0.w*k3.w;
      s[1][0] += a1.x*k0.x + a1.y*k0.y + a1.z*k0.z + a1.w*k0.w;
      s[1][1] += a1.x*k1.x + a1.y*k1.y + a1.z*k1.z + a1.w*k1.w;
      s[1][2] += a1.x*k2.x + a1.y*k2.y + a1.z*k2.z + a1.w*k2.w;
      s[1][3] += a1.x*k3.x + a1.y*k3.y + a1.z*k3.z + a1.w*k3.w;
    }
    {
      const int qg = q0 + tq;
      const int kg = kt * 64 + tk;
#pragma unroll
      for (int i = 0; i < 2; ++i) {
        float4 sv;
        sv.x = s[i][0] * 0.125f + btab[(kg + 0) - (qg + i)];
        sv.y = s[i][1] * 0.125f + btab[(kg + 1) - (qg + i)];
        sv.z = s[i][2] * 0.125f + btab[(kg + 2) - (qg + i)];
        sv.w = s[i][3] * 0.125f + btab[(kg + 3) - (qg + i)];
        *(float4*)&Sc[tq + i][tk] = sv;
      }
    }
    __syncthreads();

    // ---- tile row-max partials ----
    {
      int row = tid >> 3, sg = (tid & 7) * 8;
      float lm = -1e30f;
#pragma unroll
      for (int j = 0; j < 8; ++j) lm = fmaxf(lm, Sc[row][sg + j]);
      red[row][tid & 7] = lm;
    }
    __syncthreads();
    if (tid < 32) {
      float tmax = red[tid][0];
#pragma unroll
      for (int j = 1; j < 8; ++j) tmax = fmaxf(tmax, red[tid][j]);
      float mo = mrow[tid];
      float mn = fmaxf(mo, tmax);
      mrow[tid] = mn;
      scl[tid] = expf(mo - mn);
    }
    __syncthreads();

    // ---- exponentiate + row-sum partials ----
    {
      int row = tid >> 3, sg = (tid & 7) * 8;
      float mn = mrow[row];
      float ls = 0.f;
#pragma unroll
      for (int j = 0; j < 8; ++j) {
        float p = expf(Sc[row][sg + j] - mn);
        Sc[row][sg + j] = p;
        ls += p;
      }
      red[row][tid & 7] = ls;
    }
    __syncthreads();
    if (tid < 32) {
      float ts = 0.f;
#pragma unroll
      for (int j = 0; j < 8; ++j) ts += red[tid][j];
      lrow[tid] = lrow[tid] * scl[tid] + ts;
    }
    __syncthreads();

    // ---- PV accumulate ----
    float f0 = scl[tq], f1 = scl[tq + 1];
#pragma unroll
    for (int j = 0; j < 4; ++j) { acc[0][j] *= f0; acc[1][j] *= f1; }
#pragma unroll 8
    for (int kk = 0; kk < 64; ++kk) {
      float4 v = *(float4*)&Vs[kk][tk];
      float p0 = Sc[tq][kk], p1 = Sc[tq + 1][kk];
      acc[0][0] += p0 * v.x; acc[0][1] += p0 * v.y;
      acc[0][2] += p0 * v.z; acc[0][3] += p0 * v.w;
      acc[1][0] += p1 * v.x; acc[1][1] += p1 * v.y;
      acc[1][2] += p1 * v.z; acc[1][3] += p1 * v.w;
    }
  }
  __syncthreads();

  float inv0 = 1.0f / lrow[tq], inv1 = 1.0f / lrow[tq + 1];
  float4 o0, o1;
  o0.x = acc[0][0] * inv0; o0.y = acc[0][1] * inv0;
  o0.z = acc[0][2] * inv0; o0.w = acc[0][3] * inv0;
  o1.x = acc[1][0] * inv1; o1.y = acc[1][1] * inv1;
  o1.z = acc[1][2] * inv1; o1.w = acc[1][3] * inv1;
  size_t orow = (size_t)(b * S_ + q0 + tq) * 1024 + h * 64 + tk;
  *(float4*)&ctx[orow] = o0;
  *(float4*)&ctx[orow + 1024] = o1;
}

extern "C" void kernel_launch(void* const* d_in, const int* in_sizes, int n_in,
                              void* d_out, int out_size, void* d_ws, size_t ws_size,
                              hipStream_t stream) {
  const float* hs      = (const float*)d_in[0];
  const float* w_qkv   = (const float*)d_in[1];
  const float* b_qkv   = (const float*)d_in[2];
  const float* w_dense = (const float*)d_in[3];
  const float* b_dense = (const float*)d_in[4];
  const float* rtab    = (const float*)d_in[5];
  float* out = (float*)d_out;

  float* qkv = (float*)d_ws;                       // 4096 x 3072 fp32 (48 MB)
  float* ctx = qkv + (size_t)4096 * 3072;          // 4096 x 1024 fp32 (16 MB)
  float* biasTab = ctx + (size_t)4096 * 1024;      // 16 x 4096 fp32 (256 KB)

  hipLaunchKernelGGL(bias_table_kernel, dim3(256), dim3(256), 0, stream,
                     rtab, biasTab);
  hipLaunchKernelGGL(gemm_bias_kernel, dim3(24, 32), dim3(256), 0, stream,
                     hs, w_qkv, b_qkv, qkv, 4096, 3072, 1024);
  hipLaunchKernelGGL(attn_kernel, dim3(64, 16, 2), dim3(256), 0, stream,
                     qkv, biasTab, ctx);
  hipLaunchKernelGGL(gemm_bias_kernel, dim3(8, 32), dim3(256), 0, stream,
                     ctx, w_dense, b_dense, out, 4096, 1024, 1024);
}

// Round 2
// 653.352 us; speedup vs baseline: 2.2102x; 2.2102x over previous
//
#include <hip/hip_runtime.h>
#include <hip/hip_bf16.h>
#include <math.h>

#define S_ 2048

typedef __attribute__((ext_vector_type(8))) short bf16x8;
typedef __attribute__((ext_vector_type(4))) float f32x4;

__device__ inline unsigned short f2bf(float f) {
  union { float f; unsigned u; } x; x.f = f;
  unsigned r = x.u + 0x7fff + ((x.u >> 16) & 1);
  return (unsigned short)(r >> 16);
}

// ---------------- bias table: bias[h][rel + 2047], rel = k - q ----------------
__global__ void bias_table_kernel(const float* __restrict__ table,
                                  float* __restrict__ biasTab) {
  int idx = blockIdx.x * blockDim.x + threadIdx.x;
  if (idx >= 16 * 4096) return;
  int h = idx >> 12;
  int r = idx & 4095;
  int rel = r - 2047;                  // mem - ctx
  int bucket = rel > 0 ? 16 : 0;
  int ar = rel < 0 ? -rel : rel;
  if (ar < 8) {
    bucket += ar;
  } else {
    float tmp = logf((float)ar / 8.0f);
    float lf = tmp / 2.7725887222397811f * 8.0f;
    int large = 8 + (int)lf;
    bucket += (large < 15 ? large : 15);
  }
  biasTab[idx] = table[h * 32 + bucket];
}

// ---------------- fp32 GEMM + bias: C[M,N] = A[M,K] @ B[K,N] + bias[N] --------
// BF16OUT: write C as bf16 (packed) instead of fp32.
template <bool BF16OUT>
__global__ __launch_bounds__(256) void gemm_bias_kernel(
    const float* __restrict__ A, const float* __restrict__ Bm,
    const float* __restrict__ bias, void* __restrict__ Cout,
    int M, int N, int K) {
  __shared__ __align__(16) float As[8][128];
  __shared__ __align__(16) float Bs[8][128];
  const int tid = threadIdx.x;
  const int m0 = blockIdx.y * 128, n0 = blockIdx.x * 128;
  const int ar = tid >> 1, ak = (tid & 1) * 4;
  const int bk = tid >> 5, bn = (tid & 31) * 4;
  const int tm = (tid >> 4) * 8, tn = (tid & 15) * 8;
  float acc[8][8] = {};
  const float* Aptr = A + (size_t)(m0 + ar) * K + ak;
  const float* Bptr = Bm + (size_t)bk * N + n0 + bn;

  for (int kt = 0; kt < K; kt += 8) {
    float4 av = *(const float4*)(Aptr + kt);
    float4 bv = *(const float4*)(Bptr + (size_t)kt * N);
    As[ak + 0][ar] = av.x;
    As[ak + 1][ar] = av.y;
    As[ak + 2][ar] = av.z;
    As[ak + 3][ar] = av.w;
    *(float4*)&Bs[bk][bn] = bv;
    __syncthreads();
#pragma unroll
    for (int kk = 0; kk < 8; ++kk) {
      float4 a0 = *(float4*)&As[kk][tm];
      float4 a1 = *(float4*)&As[kk][tm + 4];
      float4 b0 = *(float4*)&Bs[kk][tn];
      float4 b1 = *(float4*)&Bs[kk][tn + 4];
      float a[8] = {a0.x, a0.y, a0.z, a0.w, a1.x, a1.y, a1.z, a1.w};
      float bb[8] = {b0.x, b0.y, b0.z, b0.w, b1.x, b1.y, b1.z, b1.w};
#pragma unroll
      for (int i = 0; i < 8; ++i)
#pragma unroll
        for (int j = 0; j < 8; ++j)
          acc[i][j] += a[i] * bb[j];
    }
    __syncthreads();
  }
  float bcol[8];
#pragma unroll
  for (int j = 0; j < 8; ++j) bcol[j] = bias[n0 + tn + j];
#pragma unroll
  for (int i = 0; i < 8; ++i) {
    if constexpr (BF16OUT) {
      typedef __attribute__((ext_vector_type(8))) unsigned short u16x8;
      u16x8 o;
#pragma unroll
      for (int j = 0; j < 8; ++j) o[j] = f2bf(acc[i][j] + bcol[j]);
      unsigned short* crow =
          (unsigned short*)Cout + (size_t)(m0 + tm + i) * N + n0 + tn;
      *(u16x8*)crow = o;
    } else {
      float4 o0, o1;
      o0.x = acc[i][0] + bcol[0]; o0.y = acc[i][1] + bcol[1];
      o0.z = acc[i][2] + bcol[2]; o0.w = acc[i][3] + bcol[3];
      o1.x = acc[i][4] + bcol[4]; o1.y = acc[i][5] + bcol[5];
      o1.z = acc[i][6] + bcol[6]; o1.w = acc[i][7] + bcol[7];
      float* crow = (float*)Cout + (size_t)(m0 + tm + i) * N + n0 + tn;
      *(float4*)crow = o0;
      *(float4*)(crow + 4) = o1;
    }
  }
}

// ---------------- bf16 MFMA flash attention ----------------
// Q-tile 64 (4 waves x 16 rows), K-tile 64. grid (32, 16, 2), block 256.
// qkvb: bf16 [4096][3072] (q|k|v each 1024 cols). ctx: fp32 [4096][1024].
__global__ __launch_bounds__(256) void attn_mfma_kernel(
    const unsigned short* __restrict__ qkvb, const float* __restrict__ biasTab,
    float* __restrict__ ctx) {
  const int qt = blockIdx.x;     // 0..31
  const int h  = blockIdx.y;
  const int b  = blockIdx.z;
  const int tid  = threadIdx.x;
  const int wave = tid >> 6;
  const int lane = tid & 63;
  const int lg = lane >> 4;      // 0..3
  const int lr = lane & 15;      // 0..15

  __shared__ __align__(16) unsigned short Ks[64][72];  // K rows, padded
  __shared__ __align__(16) unsigned short Vt[64][72];  // V transposed [d][k]
  __shared__ __align__(16) unsigned short Ps[4][16][64]; // per-wave P, swizzled
  __shared__ float biasW[128];

  const int q0 = qt * 64;

  // Q fragments (held for whole kernel): lane reads Q[lr][kh*32+lg*8 .. +7]
  bf16x8 qf[2];
  {
    const unsigned short* qrow =
        qkvb + (size_t)(b * S_ + q0 + wave * 16 + lr) * 3072 + h * 64;
#pragma unroll
    for (int kh = 0; kh < 2; ++kh)
      qf[kh] = *(const bf16x8*)(qrow + kh * 32 + lg * 8);
  }

  float mrun[4] = {-1e30f, -1e30f, -1e30f, -1e30f};
  float lrun[4] = {0.f, 0.f, 0.f, 0.f};
  f32x4 ov[4] = {};   // O accum: ov[dtile][reg]

  const size_t kvrow0 = (size_t)(b * S_) * 3072;

  for (int kb = 0; kb < S_; kb += 64) {
    __syncthreads();   // previous iteration's LDS reads complete

    // ---- stage K tile (row-major) ----
    {
      int k = tid >> 2;
      int d0 = (tid & 3) * 16;
      const unsigned short* src =
          qkvb + kvrow0 + (size_t)(kb + k) * 3072 + 1024 + h * 64 + d0;
      bf16x8 v0 = *(const bf16x8*)src;
      bf16x8 v1 = *(const bf16x8*)(src + 8);
      *(bf16x8*)&Ks[k][d0] = v0;
      *(bf16x8*)&Ks[k][d0 + 8] = v1;
    }
    // ---- stage V tile transposed ----
    {
      int k = tid & 63;
      int d0 = (tid >> 6) * 16;
      const unsigned short* src =
          qkvb + kvrow0 + (size_t)(kb + k) * 3072 + 2048 + h * 64 + d0;
      bf16x8 v0 = *(const bf16x8*)src;
      bf16x8 v1 = *(const bf16x8*)(src + 8);
#pragma unroll
      for (int j = 0; j < 8; ++j) {
        Vt[d0 + j][k] = (unsigned short)v0[j];
        Vt[d0 + 8 + j][k] = (unsigned short)v1[j];
      }
    }
    // ---- stage bias window: rel in [kb-q0-63, kb-q0+64) ----
    if (tid < 128) {
      biasW[tid] = biasTab[h * 4096 + 2047 + (kb - q0 - 63) + tid];
    }
    __syncthreads();

    // ---- QK^T: sc[kt][reg] = S[q0+wave*16+lg*4+reg][kb+kt*16+lr] ----
    f32x4 sc[4] = {};
#pragma unroll
    for (int kt = 0; kt < 4; ++kt) {
#pragma unroll
      for (int kh = 0; kh < 2; ++kh) {
        bf16x8 kf = *(bf16x8*)&Ks[kt * 16 + lr][kh * 32 + lg * 8];
        sc[kt] = __builtin_amdgcn_mfma_f32_16x16x32_bf16(qf[kh], kf, sc[kt], 0, 0, 0);
      }
    }

    // ---- bias + online softmax (register-resident stats) ----
    float pp[4][4];   // [kt][reg]
#pragma unroll
    for (int kt = 0; kt < 4; ++kt)
#pragma unroll
      for (int r = 0; r < 4; ++r)
        pp[kt][r] = sc[kt][r] * 0.125f +
                    biasW[kt * 16 + lr + 63 - wave * 16 - lg * 4 - r];

    float sclv[4];
#pragma unroll
    for (int r = 0; r < 4; ++r) {
      float tmax = fmaxf(fmaxf(pp[0][r], pp[1][r]), fmaxf(pp[2][r], pp[3][r]));
#pragma unroll
      for (int m = 1; m < 16; m <<= 1)
        tmax = fmaxf(tmax, __shfl_xor(tmax, m));
      float mo = mrun[r];
      float mn = fmaxf(mo, tmax);
      mrun[r] = mn;
      float sf = __expf(mo - mn);
      sclv[r] = sf;
      float rs = 0.f;
#pragma unroll
      for (int kt = 0; kt < 4; ++kt) {
        float e = __expf(pp[kt][r] - mn);
        pp[kt][r] = e;
        rs += e;
      }
#pragma unroll
      for (int m = 1; m < 16; m <<= 1)
        rs += __shfl_xor(rs, m);
      lrun[r] = lrun[r] * sf + rs;
    }

    // ---- write P to per-wave LDS (XOR-swizzled 8-elem blocks) ----
#pragma unroll
    for (int r = 0; r < 4; ++r) {
      int q = lg * 4 + r;
#pragma unroll
      for (int kt = 0; kt < 4; ++kt) {
        int col = kt * 16 + lr;
        int sw = (((col >> 3) ^ (q & 7)) << 3) | (col & 7);
        Ps[wave][q][sw] = f2bf(pp[kt][r]);
      }
    }

    // ---- PV: read P frags (same wave; lgkm ordering suffices) ----
    bf16x8 af[2];
#pragma unroll
    for (int kh = 0; kh < 2; ++kh) {
      int blk = (kh * 4 + lg) ^ (lr & 7);
      af[kh] = *(bf16x8*)&Ps[wave][lr][blk << 3];
    }
#pragma unroll
    for (int dt = 0; dt < 4; ++dt) {
#pragma unroll
      for (int r = 0; r < 4; ++r) ov[dt][r] *= sclv[r];
#pragma unroll
      for (int kh = 0; kh < 2; ++kh) {
        bf16x8 vf = *(bf16x8*)&Vt[dt * 16 + lr][kh * 32 + lg * 8];
        ov[dt] = __builtin_amdgcn_mfma_f32_16x16x32_bf16(af[kh], vf, ov[dt], 0, 0, 0);
      }
    }
  }

  // ---- epilogue: divide by l, store fp32 ctx ----
  float inv[4];
#pragma unroll
  for (int r = 0; r < 4; ++r) inv[r] = 1.0f / lrun[r];
#pragma unroll
  for (int dt = 0; dt < 4; ++dt) {
#pragma unroll
    for (int r = 0; r < 4; ++r) {
      size_t row = (size_t)(b * S_ + q0 + wave * 16 + lg * 4 + r);
      ctx[row * 1024 + h * 64 + dt * 16 + lr] = ov[dt][r] * inv[r];
    }
  }
}

extern "C" void kernel_launch(void* const* d_in, const int* in_sizes, int n_in,
                              void* d_out, int out_size, void* d_ws, size_t ws_size,
                              hipStream_t stream) {
  const float* hs      = (const float*)d_in[0];
  const float* w_qkv   = (const float*)d_in[1];
  const float* b_qkv   = (const float*)d_in[2];
  const float* w_dense = (const float*)d_in[3];
  const float* b_dense = (const float*)d_in[4];
  const float* rtab    = (const float*)d_in[5];
  float* out = (float*)d_out;

  unsigned short* qkvb = (unsigned short*)d_ws;              // 4096x3072 bf16 (24 MB)
  float* ctx = (float*)((char*)d_ws + (size_t)4096 * 3072 * 2); // 4096x1024 fp32 (16 MB)
  float* biasTab = ctx + (size_t)4096 * 1024;                // 16x4096 fp32 (256 KB)

  hipLaunchKernelGGL(bias_table_kernel, dim3(256), dim3(256), 0, stream,
                     rtab, biasTab);
  hipLaunchKernelGGL((gemm_bias_kernel<true>), dim3(24, 32), dim3(256), 0, stream,
                     hs, w_qkv, b_qkv, (void*)qkvb, 4096, 3072, 1024);
  hipLaunchKernelGGL(attn_mfma_kernel, dim3(32, 16, 2), dim3(256), 0, stream,
                     qkvb, biasTab, ctx);
  hipLaunchKernelGGL((gemm_bias_kernel<false>), dim3(8, 32), dim3(256), 0, stream,
                     ctx, w_dense, b_dense, (void*)out, 4096, 1024, 1024);
}

// Round 4
// 225.331 us; speedup vs baseline: 6.4085x; 2.8995x over previous
//
#include <hip/hip_runtime.h>
#include <hip/hip_bf16.h>
#include <math.h>

#define S_ 2048

typedef __attribute__((ext_vector_type(8))) short bf16x8;
typedef __attribute__((ext_vector_type(4))) float f32x4;
typedef __attribute__((ext_vector_type(8))) unsigned short u16x8;
typedef __attribute__((ext_vector_type(4))) unsigned short u16x4;

__device__ inline unsigned short f2bf(float f) {
  union { float f; unsigned u; } x; x.f = f;
  unsigned r = x.u + 0x7fff + ((x.u >> 16) & 1);
  return (unsigned short)(r >> 16);
}

__device__ __forceinline__ void gll16(const unsigned short* g, unsigned short* l) {
  __builtin_amdgcn_global_load_lds(
      (const __attribute__((address_space(1))) unsigned int*)g,
      (__attribute__((address_space(3))) unsigned int*)l, 16, 0, 0);
}

// ---------------- bias table: bias[h][rel + 2047], rel = k - q ----------------
__global__ void bias_table_kernel(const float* __restrict__ table,
                                  float* __restrict__ biasTab) {
  int idx = blockIdx.x * blockDim.x + threadIdx.x;
  if (idx >= 16 * 4096) return;
  int h = idx >> 12;
  int r = idx & 4095;
  int rel = r - 2047;                  // mem - ctx
  int bucket = rel > 0 ? 16 : 0;
  int ar = rel < 0 ? -rel : rel;
  if (ar < 8) {
    bucket += ar;
  } else {
    float tmp = logf((float)ar / 8.0f);
    float lf = tmp / 2.7725887222397811f * 8.0f;
    int large = 8 + (int)lf;
    bucket += (large < 15 ? large : 15);
  }
  biasTab[idx] = table[h * 32 + bucket];
}

// ---------------- fp32 -> bf16 elementwise (8 per thread) ----------------
__global__ __launch_bounds__(256) void cvt_bf16_kernel(
    const float* __restrict__ in, unsigned short* __restrict__ out, int n8) {
  int i = blockIdx.x * blockDim.x + threadIdx.x;
  if (i >= n8) return;
  float4 a = ((const float4*)in)[i * 2];
  float4 b = ((const float4*)in)[i * 2 + 1];
  u16x8 o;
  o[0] = f2bf(a.x); o[1] = f2bf(a.y); o[2] = f2bf(a.z); o[3] = f2bf(a.w);
  o[4] = f2bf(b.x); o[5] = f2bf(b.y); o[6] = f2bf(b.z); o[7] = f2bf(b.w);
  *(u16x8*)&out[(size_t)i * 8] = o;
}

// ---------------- fp32 [K][N] -> bf16 [N][K] transpose ----------------
__global__ __launch_bounds__(256) void transpose_cvt_kernel(
    const float* __restrict__ in, unsigned short* __restrict__ out,
    int K, int N) {
  __shared__ unsigned short tile[64][72];
  const int k0 = blockIdx.y * 64, n0 = blockIdx.x * 64;
  const int tid = threadIdx.x;
  const int rr = tid >> 4, cc = (tid & 15) * 4;
#pragma unroll
  for (int p = 0; p < 4; ++p) {
    int k = rr + p * 16;
    float4 v = *(const float4*)&in[(size_t)(k0 + k) * N + n0 + cc];
    tile[k][cc + 0] = f2bf(v.x);
    tile[k][cc + 1] = f2bf(v.y);
    tile[k][cc + 2] = f2bf(v.z);
    tile[k][cc + 3] = f2bf(v.w);
  }
  __syncthreads();
#pragma unroll
  for (int p = 0; p < 4; ++p) {
    int n = rr + p * 16;
    u16x4 o;
    o[0] = tile[cc + 0][n];
    o[1] = tile[cc + 1][n];
    o[2] = tile[cc + 2][n];
    o[3] = tile[cc + 3][n];
    *(u16x4*)&out[(size_t)(n0 + n) * K + k0 + cc] = o;
  }
}

// ---------------- bf16 MFMA GEMM: C[M][N] = A[M][K] @ Bt[N][K]^T + bias ------
// 128x128 tile, BK=32, 4 waves (2x2 of 64x64). LDS linear, source-swizzled.
template <bool BF16OUT>
__global__ __launch_bounds__(256) void gemm_mfma_kernel(
    const unsigned short* __restrict__ A, const unsigned short* __restrict__ Bt,
    const float* __restrict__ bias, void* __restrict__ Cout,
    int M, int N, int K) {
  __shared__ __align__(16) unsigned short As[128 * 32];
  __shared__ __align__(16) unsigned short Bs[128 * 32];
  const int tid = threadIdx.x;
  const int wave = tid >> 6, lane = tid & 63;
  const int lg = lane >> 4, lr = lane & 15;
  const int m0 = blockIdx.y * 128, n0 = blockIdx.x * 128;
  const int wm = (wave & 1) * 64, wn = (wave >> 1) * 64;

  f32x4 acc[4][4] = {};

  // staging: chunk i = j*256 + tid; row r = i>>2, slot s = (i&3)^(r&3)
  const int r0 = tid >> 2;
  const int sw = ((tid & 3) ^ (r0 & 3)) << 3;
  const unsigned short* aP0 = A + (size_t)(m0 + r0) * K + sw;
  const unsigned short* aP1 = A + (size_t)(m0 + 64 + r0) * K + sw;
  const unsigned short* bP0 = Bt + (size_t)(n0 + r0) * K + sw;
  const unsigned short* bP1 = Bt + (size_t)(n0 + 64 + r0) * K + sw;
  unsigned short* ldsA0 = &As[(tid & ~63) * 8];
  unsigned short* ldsA1 = &As[(256 + (tid & ~63)) * 8];
  unsigned short* ldsB0 = &Bs[(tid & ~63) * 8];
  unsigned short* ldsB1 = &Bs[(256 + (tid & ~63)) * 8];

  const int swz = (lg ^ (lr & 3)) << 3;   // frag-read slot swizzle

  for (int kt = 0; kt < K; kt += 32) {
    __syncthreads();
    gll16(aP0 + kt, ldsA0);
    gll16(aP1 + kt, ldsA1);
    gll16(bP0 + kt, ldsB0);
    gll16(bP1 + kt, ldsB1);
    __syncthreads();
    bf16x8 af[4], bfr[4];
#pragma unroll
    for (int t = 0; t < 4; ++t) {
      af[t]  = *(const bf16x8*)&As[(wm + t * 16 + lr) * 32 + swz];
      bfr[t] = *(const bf16x8*)&Bs[(wn + t * 16 + lr) * 32 + swz];
    }
#pragma unroll
    for (int i = 0; i < 4; ++i)
#pragma unroll
      for (int j = 0; j < 4; ++j)
        acc[i][j] = __builtin_amdgcn_mfma_f32_16x16x32_bf16(
            af[i], bfr[j], acc[i][j], 0, 0, 0);
  }

  float bv[4];
#pragma unroll
  for (int j = 0; j < 4; ++j) bv[j] = bias[n0 + wn + j * 16 + lr];
#pragma unroll
  for (int i = 0; i < 4; ++i) {
#pragma unroll
    for (int j = 0; j < 4; ++j) {
#pragma unroll
      for (int r = 0; r < 4; ++r) {
        int row = m0 + wm + i * 16 + lg * 4 + r;
        int col = n0 + wn + j * 16 + lr;
        float val = acc[i][j][r] + bv[j];
        if constexpr (BF16OUT)
          ((unsigned short*)Cout)[(size_t)row * N + col] = f2bf(val);
        else
          ((float*)Cout)[(size_t)row * N + col] = val;
      }
    }
  }
}

// ---------------- bf16 MFMA flash attention ----------------
// Q-tile 64 (4 waves x 16 rows), K-tile 64. grid (32, 16, 2), block 256.
__global__ __launch_bounds__(256) void attn_mfma_kernel(
    const unsigned short* __restrict__ qkvb, const float* __restrict__ biasTab,
    unsigned short* __restrict__ ctxb) {
  const int qt = blockIdx.x;
  const int h  = blockIdx.y;
  const int b  = blockIdx.z;
  const int tid  = threadIdx.x;
  const int wave = tid >> 6;
  const int lane = tid & 63;
  const int lg = lane >> 4;
  const int lr = lane & 15;

  __shared__ __align__(16) unsigned short Ks[64][72];
  __shared__ __align__(16) unsigned short Vt[64][72];
  __shared__ __align__(16) unsigned short Ps[4][16][64];
  __shared__ float biasW[128];

  const int q0 = qt * 64;

  bf16x8 qf[2];
  {
    const unsigned short* qrow =
        qkvb + (size_t)(b * S_ + q0 + wave * 16 + lr) * 3072 + h * 64;
#pragma unroll
    for (int kh = 0; kh < 2; ++kh)
      qf[kh] = *(const bf16x8*)(qrow + kh * 32 + lg * 8);
  }

  float mrun[4] = {-1e30f, -1e30f, -1e30f, -1e30f};
  float lrun[4] = {0.f, 0.f, 0.f, 0.f};
  f32x4 ov[4] = {};

  const size_t kvrow0 = (size_t)(b * S_) * 3072;

  for (int kb = 0; kb < S_; kb += 64) {
    __syncthreads();

    {
      int k = tid >> 2;
      int d0 = (tid & 3) * 16;
      const unsigned short* src =
          qkvb + kvrow0 + (size_t)(kb + k) * 3072 + 1024 + h * 64 + d0;
      bf16x8 v0 = *(const bf16x8*)src;
      bf16x8 v1 = *(const bf16x8*)(src + 8);
      *(bf16x8*)&Ks[k][d0] = v0;
      *(bf16x8*)&Ks[k][d0 + 8] = v1;
    }
    {
      int k = tid & 63;
      int d0 = (tid >> 6) * 16;
      const unsigned short* src =
          qkvb + kvrow0 + (size_t)(kb + k) * 3072 + 2048 + h * 64 + d0;
      bf16x8 v0 = *(const bf16x8*)src;
      bf16x8 v1 = *(const bf16x8*)(src + 8);
#pragma unroll
      for (int j = 0; j < 8; ++j) {
        Vt[d0 + j][k] = (unsigned short)v0[j];
        Vt[d0 + 8 + j][k] = (unsigned short)v1[j];
      }
    }
    if (tid < 128) {
      biasW[tid] = biasTab[h * 4096 + 2047 + (kb - q0 - 63) + tid];
    }
    __syncthreads();

    f32x4 sc[4] = {};
#pragma unroll
    for (int kt = 0; kt < 4; ++kt) {
#pragma unroll
      for (int kh = 0; kh < 2; ++kh) {
        bf16x8 kf = *(bf16x8*)&Ks[kt * 16 + lr][kh * 32 + lg * 8];
        sc[kt] = __builtin_amdgcn_mfma_f32_16x16x32_bf16(qf[kh], kf, sc[kt], 0, 0, 0);
      }
    }

    float pp[4][4];
#pragma unroll
    for (int kt = 0; kt < 4; ++kt)
#pragma unroll
      for (int r = 0; r < 4; ++r)
        pp[kt][r] = sc[kt][r] * 0.125f +
                    biasW[kt * 16 + lr + 63 - wave * 16 - lg * 4 - r];

    float sclv[4];
#pragma unroll
    for (int r = 0; r < 4; ++r) {
      float tmax = fmaxf(fmaxf(pp[0][r], pp[1][r]), fmaxf(pp[2][r], pp[3][r]));
#pragma unroll
      for (int m = 1; m < 16; m <<= 1)
        tmax = fmaxf(tmax, __shfl_xor(tmax, m));
      float mo = mrun[r];
      float mn = fmaxf(mo, tmax);
      mrun[r] = mn;
      float sf = __expf(mo - mn);
      sclv[r] = sf;
      float rs = 0.f;
#pragma unroll
      for (int kt = 0; kt < 4; ++kt) {
        float e = __expf(pp[kt][r] - mn);
        pp[kt][r] = e;
        rs += e;
      }
#pragma unroll
      for (int m = 1; m < 16; m <<= 1)
        rs += __shfl_xor(rs, m);
      lrun[r] = lrun[r] * sf + rs;
    }

#pragma unroll
    for (int r = 0; r < 4; ++r) {
      int q = lg * 4 + r;
#pragma unroll
      for (int kt = 0; kt < 4; ++kt) {
        int col = kt * 16 + lr;
        int sw = (((col >> 3) ^ (q & 7)) << 3) | (col & 7);
        Ps[wave][q][sw] = f2bf(pp[kt][r]);
      }
    }

    bf16x8 af[2];
#pragma unroll
    for (int kh = 0; kh < 2; ++kh) {
      int blk = (kh * 4 + lg) ^ (lr & 7);
      af[kh] = *(bf16x8*)&Ps[wave][lr][blk << 3];
    }
#pragma unroll
    for (int dt = 0; dt < 4; ++dt) {
#pragma unroll
      for (int r = 0; r < 4; ++r) ov[dt][r] *= sclv[r];
#pragma unroll
      for (int kh = 0; kh < 2; ++kh) {
        bf16x8 vf = *(bf16x8*)&Vt[dt * 16 + lr][kh * 32 + lg * 8];
        ov[dt] = __builtin_amdgcn_mfma_f32_16x16x32_bf16(af[kh], vf, ov[dt], 0, 0, 0);
      }
    }
  }

  float inv[4];
#pragma unroll
  for (int r = 0; r < 4; ++r) inv[r] = 1.0f / lrun[r];
#pragma unroll
  for (int dt = 0; dt < 4; ++dt) {
#pragma unroll
    for (int r = 0; r < 4; ++r) {
      size_t row = (size_t)(b * S_ + q0 + wave * 16 + lg * 4 + r);
      ctxb[row * 1024 + h * 64 + dt * 16 + lr] = f2bf(ov[dt][r] * inv[r]);
    }
  }
}

extern "C" void kernel_launch(void* const* d_in, const int* in_sizes, int n_in,
                              void* d_out, int out_size, void* d_ws, size_t ws_size,
                              hipStream_t stream) {
  const float* hs      = (const float*)d_in[0];
  const float* w_qkv   = (const float*)d_in[1];
  const float* b_qkv   = (const float*)d_in[2];
  const float* w_dense = (const float*)d_in[3];
  const float* b_dense = (const float*)d_in[4];
  const float* rtab    = (const float*)d_in[5];
  float* out = (float*)d_out;

  char* ws = (char*)d_ws;
  unsigned short* qkvb = (unsigned short*)ws;                          // 24 MB
  unsigned short* ctxb = (unsigned short*)(ws + (((size_t)24) << 20)); // 8 MB
  unsigned short* hsb  = (unsigned short*)(ws + (((size_t)32) << 20)); // 8 MB
  unsigned short* wqT  = (unsigned short*)(ws + (((size_t)40) << 20)); // 6 MB
  unsigned short* wdT  = (unsigned short*)(ws + (((size_t)46) << 20)); // 2 MB
  float* biasTab       = (float*)(ws + (((size_t)48) << 20));          // 256 KB

  hipLaunchKernelGGL(bias_table_kernel, dim3(256), dim3(256), 0, stream,
                     rtab, biasTab);
  hipLaunchKernelGGL(cvt_bf16_kernel, dim3(2048), dim3(256), 0, stream,
                     hs, hsb, 4096 * 1024 / 8);
  hipLaunchKernelGGL(transpose_cvt_kernel, dim3(48, 16), dim3(256), 0, stream,
                     w_qkv, wqT, 1024, 3072);
  hipLaunchKernelGGL(transpose_cvt_kernel, dim3(16, 16), dim3(256), 0, stream,
                     w_dense, wdT, 1024, 1024);
  hipLaunchKernelGGL((gemm_mfma_kernel<true>), dim3(24, 32), dim3(256), 0, stream,
                     hsb, wqT, b_qkv, (void*)qkvb, 4096, 3072, 1024);
  hipLaunchKernelGGL(attn_mfma_kernel, dim3(32, 16, 2), dim3(256), 0, stream,
                     qkvb, biasTab, ctxb);
  hipLaunchKernelGGL((gemm_mfma_kernel<false>), dim3(8, 32), dim3(256), 0, stream,
                     ctxb, wdT, b_dense, (void*)out, 4096, 1024, 1024);
}

// Round 6
// 170.462 us; speedup vs baseline: 8.4712x; 1.3219x over previous
//
#include <hip/hip_runtime.h>
#include <hip/hip_bf16.h>
#include <math.h>

#define S_ 2048

typedef __attribute__((ext_vector_type(8))) short bf16x8;
typedef __attribute__((ext_vector_type(4))) float f32x4;
typedef __attribute__((ext_vector_type(8))) unsigned short u16x8;
typedef __attribute__((ext_vector_type(4))) unsigned short u16x4;

__device__ inline unsigned short f2bf(float f) {
  union { float f; unsigned u; } x; x.f = f;
  unsigned r = x.u + 0x7fff + ((x.u >> 16) & 1);
  return (unsigned short)(r >> 16);
}

__device__ __forceinline__ void gll16(const unsigned short* g, unsigned short* l) {
  __builtin_amdgcn_global_load_lds(
      (const __attribute__((address_space(1))) unsigned int*)g,
      (__attribute__((address_space(3))) unsigned int*)l, 16, 0, 0);
}

// ---------------- bias table: bias[h][rel + 2047], rel = k - q ----------------
__global__ void bias_table_kernel(const float* __restrict__ table,
                                  float* __restrict__ biasTab) {
  int idx = blockIdx.x * blockDim.x + threadIdx.x;
  if (idx >= 16 * 4096) return;
  int h = idx >> 12;
  int r = idx & 4095;
  int rel = r - 2047;                  // mem - ctx
  int bucket = rel > 0 ? 16 : 0;
  int ar = rel < 0 ? -rel : rel;
  if (ar < 8) {
    bucket += ar;
  } else {
    float tmp = logf((float)ar / 8.0f);
    float lf = tmp / 2.7725887222397811f * 8.0f;
    int large = 8 + (int)lf;
    bucket += (large < 15 ? large : 15);
  }
  biasTab[idx] = table[h * 32 + bucket];
}

// ---------------- fp32 -> bf16 elementwise (8 per thread) ----------------
__global__ __launch_bounds__(256) void cvt_bf16_kernel(
    const float* __restrict__ in, unsigned short* __restrict__ out, int n8) {
  int i = blockIdx.x * blockDim.x + threadIdx.x;
  if (i >= n8) return;
  float4 a = ((const float4*)in)[i * 2];
  float4 b = ((const float4*)in)[i * 2 + 1];
  u16x8 o;
  o[0] = f2bf(a.x); o[1] = f2bf(a.y); o[2] = f2bf(a.z); o[3] = f2bf(a.w);
  o[4] = f2bf(b.x); o[5] = f2bf(b.y); o[6] = f2bf(b.z); o[7] = f2bf(b.w);
  *(u16x8*)&out[(size_t)i * 8] = o;
}

// ---------------- fp32 [K][N] -> bf16 [N][K] transpose ----------------
__global__ __launch_bounds__(256) void transpose_cvt_kernel(
    const float* __restrict__ in, unsigned short* __restrict__ out,
    int K, int N) {
  __shared__ unsigned short tile[64][72];
  const int k0 = blockIdx.y * 64, n0 = blockIdx.x * 64;
  const int tid = threadIdx.x;
  const int rr = tid >> 4, cc = (tid & 15) * 4;
#pragma unroll
  for (int p = 0; p < 4; ++p) {
    int k = rr + p * 16;
    float4 v = *(const float4*)&in[(size_t)(k0 + k) * N + n0 + cc];
    tile[k][cc + 0] = f2bf(v.x);
    tile[k][cc + 1] = f2bf(v.y);
    tile[k][cc + 2] = f2bf(v.z);
    tile[k][cc + 3] = f2bf(v.w);
  }
  __syncthreads();
#pragma unroll
  for (int p = 0; p < 4; ++p) {
    int n = rr + p * 16;
    u16x4 o;
    o[0] = tile[cc + 0][n];
    o[1] = tile[cc + 1][n];
    o[2] = tile[cc + 2][n];
    o[3] = tile[cc + 3][n];
    *(u16x4*)&out[(size_t)(n0 + n) * K + k0 + cc] = o;
  }
}

// ---------------- bf16 MFMA GEMM: C[M][N] = A[M][K] @ Bt[N][K]^T + bias ------
template <bool BF16OUT>
__global__ __launch_bounds__(256) void gemm_mfma_kernel(
    const unsigned short* __restrict__ A, const unsigned short* __restrict__ Bt,
    const float* __restrict__ bias, void* __restrict__ Cout,
    int M, int N, int K) {
  __shared__ __align__(16) unsigned short As[128 * 32];
  __shared__ __align__(16) unsigned short Bs[128 * 32];
  const int tid = threadIdx.x;
  const int wave = tid >> 6, lane = tid & 63;
  const int lg = lane >> 4, lr = lane & 15;
  const int m0 = blockIdx.y * 128, n0 = blockIdx.x * 128;
  const int wm = (wave & 1) * 64, wn = (wave >> 1) * 64;

  f32x4 acc[4][4] = {};

  const int r0 = tid >> 2;
  const int sw = ((tid & 3) ^ (r0 & 3)) << 3;
  const unsigned short* aP0 = A + (size_t)(m0 + r0) * K + sw;
  const unsigned short* aP1 = A + (size_t)(m0 + 64 + r0) * K + sw;
  const unsigned short* bP0 = Bt + (size_t)(n0 + r0) * K + sw;
  const unsigned short* bP1 = Bt + (size_t)(n0 + 64 + r0) * K + sw;
  unsigned short* ldsA0 = &As[(tid & ~63) * 8];
  unsigned short* ldsA1 = &As[(256 + (tid & ~63)) * 8];
  unsigned short* ldsB0 = &Bs[(tid & ~63) * 8];
  unsigned short* ldsB1 = &Bs[(256 + (tid & ~63)) * 8];

  const int swz = (lg ^ (lr & 3)) << 3;

  for (int kt = 0; kt < K; kt += 32) {
    __syncthreads();
    gll16(aP0 + kt, ldsA0);
    gll16(aP1 + kt, ldsA1);
    gll16(bP0 + kt, ldsB0);
    gll16(bP1 + kt, ldsB1);
    __syncthreads();
    bf16x8 af[4], bfr[4];
#pragma unroll
    for (int t = 0; t < 4; ++t) {
      af[t]  = *(const bf16x8*)&As[(wm + t * 16 + lr) * 32 + swz];
      bfr[t] = *(const bf16x8*)&Bs[(wn + t * 16 + lr) * 32 + swz];
    }
#pragma unroll
    for (int i = 0; i < 4; ++i)
#pragma unroll
      for (int j = 0; j < 4; ++j)
        acc[i][j] = __builtin_amdgcn_mfma_f32_16x16x32_bf16(
            af[i], bfr[j], acc[i][j], 0, 0, 0);
  }

  float bv[4];
#pragma unroll
  for (int j = 0; j < 4; ++j) bv[j] = bias[n0 + wn + j * 16 + lr];
#pragma unroll
  for (int i = 0; i < 4; ++i) {
#pragma unroll
    for (int j = 0; j < 4; ++j) {
#pragma unroll
      for (int r = 0; r < 4; ++r) {
        int row = m0 + wm + i * 16 + lg * 4 + r;
        int col = n0 + wn + j * 16 + lr;
        float val = acc[i][j][r] + bv[j];
        if constexpr (BF16OUT)
          ((unsigned short*)Cout)[(size_t)row * N + col] = f2bf(val);
        else
          ((float*)Cout)[(size_t)row * N + col] = val;
      }
    }
  }
}

// ---------------- V permute pre-pass ----------------
// vP[bb][h][d][k'] : per 64-k tile t, 16B-slot phys_s = s ^ (d&7), slot s=4w+lg
// holds elems e=0..7 with k_within = w*32 + (e>>2)*16 + lg*4 + (e&3).
// grid (32 tiles, 16 h, 2 b), block 256.
__global__ __launch_bounds__(256) void vperm_kernel(
    const unsigned short* __restrict__ qkvb, unsigned short* __restrict__ vP) {
  const int t = blockIdx.x, h = blockIdx.y, bb = blockIdx.z;
  __shared__ unsigned short tile[64][72];
  const int tid = threadIdx.x;
  {
    int k = tid >> 2, c = (tid & 3) * 16;
    const unsigned short* src =
        qkvb + (size_t)(bb * S_ + t * 64 + k) * 3072 + 2048 + h * 64 + c;
    *(bf16x8*)&tile[k][c] = *(const bf16x8*)src;
    *(bf16x8*)&tile[k][c + 8] = *(const bf16x8*)(src + 8);
  }
  __syncthreads();
  const int d = tid >> 2, m0 = (tid & 3) * 16;
  unsigned short* dst =
      vP + ((size_t)((bb * 16 + h) * 64 + d)) * S_ + t * 64 + m0;
#pragma unroll
  for (int half = 0; half < 2; ++half) {
    u16x8 o;
#pragma unroll
    for (int j = 0; j < 8; ++j) {
      int m = m0 + half * 8 + j;
      int phys_s = m >> 3, e = m & 7;
      int s = phys_s ^ (d & 7);
      int w = s >> 2, lg = s & 3;
      int kw = w * 32 + (e >> 2) * 16 + lg * 4 + (e & 3);
      o[j] = tile[kw][d];
    }
    *(u16x8*)(dst + half * 8) = o;
  }
}

// ---------------- bf16 MFMA flash attention v3 ----------------
// Swapped QK^T (S^T in regs), reg-resident P, permuted-V via vP + gll16.
// Q-tile 128 (4 waves x 32 rows), K-tile 64. grid 512, block 256.
__global__ __launch_bounds__(256) void attn_mfma3_kernel(
    const unsigned short* __restrict__ qkvb, const unsigned short* __restrict__ vP,
    const float* __restrict__ biasTab, unsigned short* __restrict__ ctxb) {
  // bijective XCD swizzle: 512 wgs, 64 per XCD
  const int wg0 = blockIdx.x;
  const int wg = (wg0 & 7) * 64 + (wg0 >> 3);
  const int qt = wg & 15;
  const int h  = (wg >> 4) & 15;
  const int bb = wg >> 8;

  const int tid = threadIdx.x;
  const int wave = tid >> 6;
  const int lane = tid & 63;
  const int lg = lane >> 4;
  const int lr = lane & 15;

  __shared__ __align__(16) unsigned short Klds[2][4096];  // [64 k][8 blk][8] swz
  __shared__ __align__(16) unsigned short Vlds[2][4096];  // [64 d][8 slot][8] swz
  __shared__ float biasW[2][192];

  const int q0 = qt * 128;
  const int qw = q0 + wave * 32;

  // Q fragments (B operand): qf[qs][kh] = Q[qw+qs*16+lr][kh*32+lg*8 ..+7]
  bf16x8 qf[2][2];
#pragma unroll
  for (int qs = 0; qs < 2; ++qs)
#pragma unroll
    for (int kh = 0; kh < 2; ++kh)
      qf[qs][kh] = *(const bf16x8*)(qkvb +
          (size_t)(bb * S_ + qw + qs * 16 + lr) * 3072 + h * 64 + kh * 32 + lg * 8);

  float mrun[2] = {-1e30f, -1e30f};
  float lrun[2] = {0.f, 0.f};
  f32x4 ov[2][4] = {};

  // ---- staging geometry ----
  // K chunks c in {tid, tid+256}: k=c>>3, phys blk pb=c&7, src blk = pb^(k&7)
  const int kk0 = tid >> 3,         kpb0 = tid & 7;
  const int kk1 = (tid + 256) >> 3, kpb1 = (tid + 256) & 7;
  const unsigned short* kptr0 = qkvb + (size_t)(bb * S_ + kk0) * 3072 + 1024 +
                                h * 64 + (kpb0 ^ (kk0 & 7)) * 8;
  const unsigned short* kptr1 = qkvb + (size_t)(bb * S_ + kk1) * 3072 + 1024 +
                                h * 64 + (kpb1 ^ (kk1 & 7)) * 8;
  // V chunks: d=c>>3, slot=c&7 (vP already phys-swizzled -> pure linear copy)
  const unsigned short* vPbase = vP + ((size_t)((bb * 16 + h) * 64)) * S_;
  const unsigned short* vptr0 = vPbase + (size_t)(tid >> 3) * S_ + (tid & 7) * 8;
  const unsigned short* vptr1 = vPbase + (size_t)((tid + 256) >> 3) * S_ +
                                ((tid + 256) & 7) * 8;
  const float* btabH = biasTab + h * 4096 + 2047;

  // ---- prologue: stage tile 0 ----
  gll16(kptr0, &Klds[0][wave * 512]);
  gll16(kptr1, &Klds[0][2048 + wave * 512]);
  gll16(vptr0, &Vlds[0][wave * 512]);
  gll16(vptr1, &Vlds[0][2048 + wave * 512]);
  if (tid < 192) biasW[0][tid] = btabH[-q0 - 127 + tid];

  for (int t = 0; t < 32; ++t) {
    const int cur = t & 1;
    __syncthreads();   // drains gll16 (vmcnt) + bias writes; swaps buffers

    if (t < 31) {
      const size_t kadv = (size_t)(t + 1) * 64 * 3072;
      gll16(kptr0 + kadv, &Klds[cur ^ 1][wave * 512]);
      gll16(kptr1 + kadv, &Klds[cur ^ 1][2048 + wave * 512]);
      gll16(vptr0 + (t + 1) * 64, &Vlds[cur ^ 1][wave * 512]);
      gll16(vptr1 + (t + 1) * 64, &Vlds[cur ^ 1][2048 + wave * 512]);
      if (tid < 192)
        biasW[cur ^ 1][tid] = btabH[(t + 1) * 64 - q0 - 127 + tid];
    }

    // ---- QK^T swapped: sc[qs][kt][r] = S[kb+kt*16+lg*4+r][qw+qs*16+lr] ----
    f32x4 sc[2][4] = {};
#pragma unroll
    for (int kt = 0; kt < 4; ++kt) {
      const unsigned short* kr = &Klds[cur][(kt * 16 + lr) * 64];
      bf16x8 kf0 = *(const bf16x8*)(kr + ((lg)     ^ (lr & 7)) * 8);
      bf16x8 kf1 = *(const bf16x8*)(kr + ((4 + lg) ^ (lr & 7)) * 8);
#pragma unroll
      for (int qs = 0; qs < 2; ++qs) {
        sc[qs][kt] = __builtin_amdgcn_mfma_f32_16x16x32_bf16(kf0, qf[qs][0], sc[qs][kt], 0, 0, 0);
        sc[qs][kt] = __builtin_amdgcn_mfma_f32_16x16x32_bf16(kf1, qf[qs][1], sc[qs][kt], 0, 0, 0);
      }
    }

    // ---- bias + online softmax (in-lane over 16 k, 2 shuffles over lg) ----
    float pp[2][4][4];
    float sf[2];
#pragma unroll
    for (int qs = 0; qs < 2; ++qs) {
      const int bidx = 127 + lg * 4 - wave * 32 - qs * 16 - lr;
#pragma unroll
      for (int kt = 0; kt < 4; ++kt)
#pragma unroll
        for (int r = 0; r < 4; ++r)
          pp[qs][kt][r] = sc[qs][kt][r] * 0.125f + biasW[cur][bidx + kt * 16 + r];

      float tm = pp[qs][0][0];
#pragma unroll
      for (int kt = 0; kt < 4; ++kt)
#pragma unroll
        for (int r = 0; r < 4; ++r)
          tm = fmaxf(tm, pp[qs][kt][r]);
      tm = fmaxf(tm, __shfl_xor(tm, 16));
      tm = fmaxf(tm, __shfl_xor(tm, 32));
      float mo = mrun[qs];
      float mn = fmaxf(mo, tm);
      mrun[qs] = mn;
      sf[qs] = __expf(mo - mn);
      float rs = 0.f;
#pragma unroll
      for (int kt = 0; kt < 4; ++kt)
#pragma unroll
        for (int r = 0; r < 4; ++r) {
          float e = __expf(pp[qs][kt][r] - mn);
          pp[qs][kt][r] = e;
          rs += e;
        }
      rs += __shfl_xor(rs, 16);
      rs += __shfl_xor(rs, 32);
      lrun[qs] = lrun[qs] * sf[qs] + rs;
    }

    // ---- pack P -> bf16 A-frags; kappa-map = (e>>2)*16 + lg*4 + (e&3) ----
    bf16x8 af[2][2];
#pragma unroll
    for (int qs = 0; qs < 2; ++qs)
#pragma unroll
      for (int kh = 0; kh < 2; ++kh)
#pragma unroll
        for (int e = 0; e < 8; ++e)
          af[qs][kh][e] = (short)f2bf(pp[qs][2 * kh + (e >> 2)][e & 3]);

    // ---- rescale O accumulators (scl for q = lg*4+r via shfl) ----
#pragma unroll
    for (int qs = 0; qs < 2; ++qs)
#pragma unroll
      for (int r = 0; r < 4; ++r) {
        float sq = __shfl(sf[qs], (lane & 48) | (lg * 4 + r));
#pragma unroll
        for (int db = 0; db < 4; ++db) ov[qs][db][r] *= sq;
      }

    // ---- V fragments: plain b128 reads, same kappa permutation as af ----
    bf16x8 vf[2][4];
#pragma unroll
    for (int kh = 0; kh < 2; ++kh)
#pragma unroll
      for (int db = 0; db < 4; ++db)
        vf[kh][db] = *(const bf16x8*)&Vlds[cur][
            (db * 16 + lr) * 64 + ((4 * kh + lg) ^ (lr & 7)) * 8];

    // ---- PV ----
#pragma unroll
    for (int qs = 0; qs < 2; ++qs)
#pragma unroll
      for (int kh = 0; kh < 2; ++kh)
#pragma unroll
        for (int db = 0; db < 4; ++db)
          ov[qs][db] = __builtin_amdgcn_mfma_f32_16x16x32_bf16(
              af[qs][kh], vf[kh][db], ov[qs][db], 0, 0, 0);
  }

  // ---- epilogue ----
#pragma unroll
  for (int qs = 0; qs < 2; ++qs) {
    float invl = 1.0f / lrun[qs];
#pragma unroll
    for (int r = 0; r < 4; ++r) {
      float iv = __shfl(invl, (lane & 48) | (lg * 4 + r));
      size_t row = (size_t)(bb * S_ + qw + qs * 16 + lg * 4 + r);
#pragma unroll
      for (int db = 0; db < 4; ++db)
        ctxb[row * 1024 + h * 64 + db * 16 + lr] = f2bf(ov[qs][db][r] * iv);
    }
  }
}

extern "C" void kernel_launch(void* const* d_in, const int* in_sizes, int n_in,
                              void* d_out, int out_size, void* d_ws, size_t ws_size,
                              hipStream_t stream) {
  const float* hs      = (const float*)d_in[0];
  const float* w_qkv   = (const float*)d_in[1];
  const float* b_qkv   = (const float*)d_in[2];
  const float* w_dense = (const float*)d_in[3];
  const float* b_dense = (const float*)d_in[4];
  const float* rtab    = (const float*)d_in[5];
  float* out = (float*)d_out;

  char* ws = (char*)d_ws;
  unsigned short* qkvb = (unsigned short*)ws;                          // 24 MB
  unsigned short* ctxb = (unsigned short*)(ws + (((size_t)24) << 20)); // 8 MB
  unsigned short* hsb  = (unsigned short*)(ws + (((size_t)32) << 20)); // 8 MB
  unsigned short* wqT  = (unsigned short*)(ws + (((size_t)40) << 20)); // 6 MB
  unsigned short* wdT  = (unsigned short*)(ws + (((size_t)46) << 20)); // 2 MB
  unsigned short* vP   = (unsigned short*)(ws + (((size_t)48) << 20)); // 8 MB
  float* biasTab       = (float*)(ws + (((size_t)56) << 20));          // 256 KB

  hipLaunchKernelGGL(bias_table_kernel, dim3(256), dim3(256), 0, stream,
                     rtab, biasTab);
  hipLaunchKernelGGL(cvt_bf16_kernel, dim3(2048), dim3(256), 0, stream,
                     hs, hsb, 4096 * 1024 / 8);
  hipLaunchKernelGGL(transpose_cvt_kernel, dim3(48, 16), dim3(256), 0, stream,
                     w_qkv, wqT, 1024, 3072);
  hipLaunchKernelGGL(transpose_cvt_kernel, dim3(16, 16), dim3(256), 0, stream,
                     w_dense, wdT, 1024, 1024);
  hipLaunchKernelGGL((gemm_mfma_kernel<true>), dim3(24, 32), dim3(256), 0, stream,
                     hsb, wqT, b_qkv, (void*)qkvb, 4096, 3072, 1024);
  hipLaunchKernelGGL(vperm_kernel, dim3(32, 16, 2), dim3(256), 0, stream,
                     qkvb, vP);
  hipLaunchKernelGGL(attn_mfma3_kernel, dim3(512), dim3(256), 0, stream,
                     qkvb, vP, biasTab, ctxb);
  hipLaunchKernelGGL((gemm_mfma_kernel<false>), dim3(8, 32), dim3(256), 0, stream,
                     ctxb, wdT, b_dense, (void*)out, 4096, 1024, 1024);
}

// Round 7
// 154.073 us; speedup vs baseline: 9.3723x; 1.1064x over previous
//
#include <hip/hip_runtime.h>
#include <hip/hip_bf16.h>
#include <math.h>

#define S_ 2048

typedef __attribute__((ext_vector_type(8))) short bf16x8;
typedef __attribute__((ext_vector_type(4))) float f32x4;
typedef __attribute__((ext_vector_type(8))) unsigned short u16x8;
typedef __attribute__((ext_vector_type(4))) unsigned short u16x4;

__device__ inline unsigned short f2bf(float f) {
  union { float f; unsigned u; } x; x.f = f;
  unsigned r = x.u + 0x7fff + ((x.u >> 16) & 1);
  return (unsigned short)(r >> 16);
}

__device__ __forceinline__ void gll16(const unsigned short* g, unsigned short* l) {
  __builtin_amdgcn_global_load_lds(
      (const __attribute__((address_space(1))) unsigned int*)g,
      (__attribute__((address_space(3))) unsigned int*)l, 16, 0, 0);
}

// ---------------- bias table: bias[h][rel + 2047], rel = k - q ----------------
__global__ void bias_table_kernel(const float* __restrict__ table,
                                  float* __restrict__ biasTab) {
  int idx = blockIdx.x * blockDim.x + threadIdx.x;
  if (idx >= 16 * 4096) return;
  int h = idx >> 12;
  int r = idx & 4095;
  int rel = r - 2047;                  // mem - ctx
  int bucket = rel > 0 ? 16 : 0;
  int ar = rel < 0 ? -rel : rel;
  if (ar < 8) {
    bucket += ar;
  } else {
    float tmp = logf((float)ar / 8.0f);
    float lf = tmp / 2.7725887222397811f * 8.0f;
    int large = 8 + (int)lf;
    bucket += (large < 15 ? large : 15);
  }
  biasTab[idx] = table[h * 32 + bucket];
}

// ---------------- fp32 -> bf16 elementwise (8 per thread) ----------------
__global__ __launch_bounds__(256) void cvt_bf16_kernel(
    const float* __restrict__ in, unsigned short* __restrict__ out, int n8) {
  int i = blockIdx.x * blockDim.x + threadIdx.x;
  if (i >= n8) return;
  float4 a = ((const float4*)in)[i * 2];
  float4 b = ((const float4*)in)[i * 2 + 1];
  u16x8 o;
  o[0] = f2bf(a.x); o[1] = f2bf(a.y); o[2] = f2bf(a.z); o[3] = f2bf(a.w);
  o[4] = f2bf(b.x); o[5] = f2bf(b.y); o[6] = f2bf(b.z); o[7] = f2bf(b.w);
  *(u16x8*)&out[(size_t)i * 8] = o;
}

// ---------------- fp32 [K][N] -> bf16 [N][K] transpose ----------------
__global__ __launch_bounds__(256) void transpose_cvt_kernel(
    const float* __restrict__ in, unsigned short* __restrict__ out,
    int K, int N) {
  __shared__ unsigned short tile[64][72];
  const int k0 = blockIdx.y * 64, n0 = blockIdx.x * 64;
  const int tid = threadIdx.x;
  const int rr = tid >> 4, cc = (tid & 15) * 4;
#pragma unroll
  for (int p = 0; p < 4; ++p) {
    int k = rr + p * 16;
    float4 v = *(const float4*)&in[(size_t)(k0 + k) * N + n0 + cc];
    tile[k][cc + 0] = f2bf(v.x);
    tile[k][cc + 1] = f2bf(v.y);
    tile[k][cc + 2] = f2bf(v.z);
    tile[k][cc + 3] = f2bf(v.w);
  }
  __syncthreads();
#pragma unroll
  for (int p = 0; p < 4; ++p) {
    int n = rr + p * 16;
    u16x4 o;
    o[0] = tile[cc + 0][n];
    o[1] = tile[cc + 1][n];
    o[2] = tile[cc + 2][n];
    o[3] = tile[cc + 3][n];
    *(u16x4*)&out[(size_t)(n0 + n) * K + k0 + cc] = o;
  }
}

// ---------------- bf16 MFMA GEMM: C[M][N] = A[M][K] @ Bt[N][K]^T + bias ------
template <bool BF16OUT>
__global__ __launch_bounds__(256) void gemm_mfma_kernel(
    const unsigned short* __restrict__ A, const unsigned short* __restrict__ Bt,
    const float* __restrict__ bias, void* __restrict__ Cout,
    int M, int N, int K) {
  __shared__ __align__(16) unsigned short As[128 * 32];
  __shared__ __align__(16) unsigned short Bs[128 * 32];
  const int tid = threadIdx.x;
  const int wave = tid >> 6, lane = tid & 63;
  const int lg = lane >> 4, lr = lane & 15;
  const int m0 = blockIdx.y * 128, n0 = blockIdx.x * 128;
  const int wm = (wave & 1) * 64, wn = (wave >> 1) * 64;

  f32x4 acc[4][4] = {};

  const int r0 = tid >> 2;
  const int sw = ((tid & 3) ^ (r0 & 3)) << 3;
  const unsigned short* aP0 = A + (size_t)(m0 + r0) * K + sw;
  const unsigned short* aP1 = A + (size_t)(m0 + 64 + r0) * K + sw;
  const unsigned short* bP0 = Bt + (size_t)(n0 + r0) * K + sw;
  const unsigned short* bP1 = Bt + (size_t)(n0 + 64 + r0) * K + sw;
  unsigned short* ldsA0 = &As[(tid & ~63) * 8];
  unsigned short* ldsA1 = &As[(256 + (tid & ~63)) * 8];
  unsigned short* ldsB0 = &Bs[(tid & ~63) * 8];
  unsigned short* ldsB1 = &Bs[(256 + (tid & ~63)) * 8];

  const int swz = (lg ^ (lr & 3)) << 3;

  for (int kt = 0; kt < K; kt += 32) {
    __syncthreads();
    gll16(aP0 + kt, ldsA0);
    gll16(aP1 + kt, ldsA1);
    gll16(bP0 + kt, ldsB0);
    gll16(bP1 + kt, ldsB1);
    __syncthreads();
    bf16x8 af[4], bfr[4];
#pragma unroll
    for (int t = 0; t < 4; ++t) {
      af[t]  = *(const bf16x8*)&As[(wm + t * 16 + lr) * 32 + swz];
      bfr[t] = *(const bf16x8*)&Bs[(wn + t * 16 + lr) * 32 + swz];
    }
#pragma unroll
    for (int i = 0; i < 4; ++i)
#pragma unroll
      for (int j = 0; j < 4; ++j)
        acc[i][j] = __builtin_amdgcn_mfma_f32_16x16x32_bf16(
            af[i], bfr[j], acc[i][j], 0, 0, 0);
  }

  float bv[4];
#pragma unroll
  for (int j = 0; j < 4; ++j) bv[j] = bias[n0 + wn + j * 16 + lr];
#pragma unroll
  for (int i = 0; i < 4; ++i) {
#pragma unroll
    for (int j = 0; j < 4; ++j) {
#pragma unroll
      for (int r = 0; r < 4; ++r) {
        int row = m0 + wm + i * 16 + lg * 4 + r;
        int col = n0 + wn + j * 16 + lr;
        float val = acc[i][j][r] + bv[j];
        if constexpr (BF16OUT)
          ((unsigned short*)Cout)[(size_t)row * N + col] = f2bf(val);
        else
          ((float*)Cout)[(size_t)row * N + col] = val;
      }
    }
  }
}

// ---------------- V permute pre-pass ----------------
// vP[bb][h][d][k'] : per 64-k tile t, 16B-slot phys_s = s ^ (d&7), slot s=4w+lg
// holds elems e=0..7 with k_within = w*32 + (e>>2)*16 + lg*4 + (e&3).
__global__ __launch_bounds__(256) void vperm_kernel(
    const unsigned short* __restrict__ qkvb, unsigned short* __restrict__ vP) {
  const int t = blockIdx.x, h = blockIdx.y, bb = blockIdx.z;
  __shared__ unsigned short tile[64][72];
  const int tid = threadIdx.x;
  {
    int k = tid >> 2, c = (tid & 3) * 16;
    const unsigned short* src =
        qkvb + (size_t)(bb * S_ + t * 64 + k) * 3072 + 2048 + h * 64 + c;
    *(bf16x8*)&tile[k][c] = *(const bf16x8*)src;
    *(bf16x8*)&tile[k][c + 8] = *(const bf16x8*)(src + 8);
  }
  __syncthreads();
  const int d = tid >> 2, m0 = (tid & 3) * 16;
  unsigned short* dst =
      vP + ((size_t)((bb * 16 + h) * 64 + d)) * S_ + t * 64 + m0;
#pragma unroll
  for (int half = 0; half < 2; ++half) {
    u16x8 o;
#pragma unroll
    for (int j = 0; j < 8; ++j) {
      int m = m0 + half * 8 + j;
      int phys_s = m >> 3, e = m & 7;
      int s = phys_s ^ (d & 7);
      int w = s >> 2, lg = s & 3;
      int kw = w * 32 + (e >> 2) * 16 + lg * 4 + (e & 3);
      o[j] = tile[kw][d];
    }
    *(u16x8*)(dst + half * 8) = o;
  }
}

// ---------------- bf16 MFMA flash attention v4 ----------------
// 8 waves x 16 q-rows (q-tile 128), K-tile 64. 512 threads, grid 512.
// Swapped QK^T, reg P, cvt_pk pack, defer-max, uniform-bias fast path.
__global__ __launch_bounds__(512) void attn_mfma4_kernel(
    const unsigned short* __restrict__ qkvb, const unsigned short* __restrict__ vP,
    const float* __restrict__ biasTab, unsigned short* __restrict__ ctxb) {
  // bijective XCD swizzle: 512 wgs, 64 per XCD
  const int wg0 = blockIdx.x;
  const int wg = (wg0 & 7) * 64 + (wg0 >> 3);
  const int qt = wg & 15;
  const int h  = (wg >> 4) & 15;
  const int bb = wg >> 8;

  const int tid = threadIdx.x;
  const int wave = tid >> 6;     // 0..7
  const int lane = tid & 63;
  const int lg = lane >> 4;
  const int lr = lane & 15;

  __shared__ __align__(16) unsigned short Klds[2][4096];  // [64 k][8 blk][8] swz
  __shared__ __align__(16) unsigned short Vlds[2][4096];  // [64 d][8 slot][8] swz
  __shared__ float biasW[2][192];

  const int q0 = qt * 128;
  const int qw = q0 + wave * 16;

  // Q fragments (B operand): qf[kh] = Q[qw+lr][kh*32+lg*8 ..+7]
  bf16x8 qf[2];
#pragma unroll
  for (int kh = 0; kh < 2; ++kh)
    qf[kh] = *(const bf16x8*)(qkvb +
        (size_t)(bb * S_ + qw + lr) * 3072 + h * 64 + kh * 32 + lg * 8);

  float mrun = -1e30f;
  float lrun = 0.f;
  f32x4 ov[4] = {};

  // ---- staging geometry: thread stages chunk c = tid (512 x 16B per tile) ----
  const int kk = tid >> 3, kpb = tid & 7;
  const unsigned short* kptr = qkvb + (size_t)(bb * S_ + kk) * 3072 + 1024 +
                               h * 64 + (kpb ^ (kk & 7)) * 8;
  const unsigned short* vptr = vP + ((size_t)((bb * 16 + h) * 64 + (tid >> 3))) * S_ +
                               (tid & 7) * 8;
  const float* btabH = biasTab + h * 4096 + 2047;

  // non-uniform-bias predicate for tile tt (rel range [tt*64-q0-127, tt*64-q0+63])
  auto nonuni = [&](int tt) {
    int rl = tt * 64 - q0;
    return !((rl - 127 >= 91) || (rl + 63 <= -91));
  };

  // ---- prologue: stage tile 0 ----
  gll16(kptr, &Klds[0][(tid & ~63) * 8]);
  gll16(vptr, &Vlds[0][(tid & ~63) * 8]);
  if (nonuni(0) && tid < 192) biasW[0][tid] = btabH[-q0 - 127 + tid];

  for (int t = 0; t < 32; ++t) {
    const int cur = t & 1;
    __syncthreads();   // drains gll16 (vmcnt) + bias writes; swaps buffers

    if (t < 31) {
      const size_t kadv = (size_t)(t + 1) * 64 * 3072;
      gll16(kptr + kadv, &Klds[cur ^ 1][(tid & ~63) * 8]);
      gll16(vptr + (t + 1) * 64, &Vlds[cur ^ 1][(tid & ~63) * 8]);
      if (nonuni(t + 1) && tid < 192)
        biasW[cur ^ 1][tid] = btabH[(t + 1) * 64 - q0 - 127 + tid];
    }

    // ---- QK^T swapped: sc[kt][r] = S[kb+kt*16+lg*4+r][qw+lr] ----
    f32x4 sc[4] = {};
#pragma unroll
    for (int kt = 0; kt < 4; ++kt) {
      const unsigned short* kr = &Klds[cur][(kt * 16 + lr) * 64];
      bf16x8 kf0 = *(const bf16x8*)(kr + ((lg)     ^ (lr & 7)) * 8);
      bf16x8 kf1 = *(const bf16x8*)(kr + ((4 + lg) ^ (lr & 7)) * 8);
      sc[kt] = __builtin_amdgcn_mfma_f32_16x16x32_bf16(kf0, qf[0], sc[kt], 0, 0, 0);
      sc[kt] = __builtin_amdgcn_mfma_f32_16x16x32_bf16(kf1, qf[1], sc[kt], 0, 0, 0);
    }

    // ---- bias ----
    float pp[4][4];
    if (nonuni(t)) {
      const int bidx = 127 + lg * 4 - wave * 16 - lr;
#pragma unroll
      for (int kt = 0; kt < 4; ++kt)
#pragma unroll
        for (int r = 0; r < 4; ++r)
          pp[kt][r] = sc[kt][r] * 0.125f + biasW[cur][bidx + kt * 16 + r];
    } else {
      const float cb = btabH[t * 64 - q0];   // bucket saturated: tile-constant
#pragma unroll
      for (int kt = 0; kt < 4; ++kt)
#pragma unroll
        for (int r = 0; r < 4; ++r)
          pp[kt][r] = sc[kt][r] * 0.125f + cb;
    }

    // ---- row max: binary tree + 2 shuffles ----
    float mx[8];
#pragma unroll
    for (int i = 0; i < 8; ++i)
      mx[i] = fmaxf(pp[i >> 1][(i & 1) * 2], pp[i >> 1][(i & 1) * 2 + 1]);
    float m01 = fmaxf(mx[0], mx[1]), m23 = fmaxf(mx[2], mx[3]);
    float m45 = fmaxf(mx[4], mx[5]), m67 = fmaxf(mx[6], mx[7]);
    float tm = fmaxf(fmaxf(m01, m23), fmaxf(m45, m67));
    tm = fmaxf(tm, __shfl_xor(tm, 16));
    tm = fmaxf(tm, __shfl_xor(tm, 32));

    // ---- defer-max (T13, THR=8) ----
    if (!__all(tm <= mrun + 8.f)) {
      float mn = fmaxf(mrun, tm);
      float sfv = __expf(mrun - mn);
      mrun = mn;
      lrun *= sfv;
#pragma unroll
      for (int r = 0; r < 4; ++r) {
        float sq = __shfl(sfv, (lane & 48) | (lg * 4 + r));
#pragma unroll
        for (int db = 0; db < 4; ++db) ov[db][r] *= sq;
      }
    }

    // ---- exp + row sum (tree) ----
#pragma unroll
    for (int kt = 0; kt < 4; ++kt)
#pragma unroll
      for (int r = 0; r < 4; ++r)
        pp[kt][r] = __expf(pp[kt][r] - mrun);
    float s8[8];
#pragma unroll
    for (int i = 0; i < 8; ++i)
      s8[i] = pp[i >> 1][(i & 1) * 2] + pp[i >> 1][(i & 1) * 2 + 1];
    float s01 = s8[0] + s8[1], s23 = s8[2] + s8[3];
    float s45 = s8[4] + s8[5], s67 = s8[6] + s8[7];
    float rs = (s01 + s23) + (s45 + s67);
    rs += __shfl_xor(rs, 16);
    rs += __shfl_xor(rs, 32);
    lrun += rs;

    // ---- pack P -> bf16 A-frags via v_cvt_pk_bf16_f32 ----
    union { bf16x8 v; unsigned u[4]; } pk[2];
#pragma unroll
    for (int kh = 0; kh < 2; ++kh) {
      asm("v_cvt_pk_bf16_f32 %0, %1, %2"
          : "=v"(pk[kh].u[0]) : "v"(pp[2 * kh][0]), "v"(pp[2 * kh][1]));
      asm("v_cvt_pk_bf16_f32 %0, %1, %2"
          : "=v"(pk[kh].u[1]) : "v"(pp[2 * kh][2]), "v"(pp[2 * kh][3]));
      asm("v_cvt_pk_bf16_f32 %0, %1, %2"
          : "=v"(pk[kh].u[2]) : "v"(pp[2 * kh + 1][0]), "v"(pp[2 * kh + 1][1]));
      asm("v_cvt_pk_bf16_f32 %0, %1, %2"
          : "=v"(pk[kh].u[3]) : "v"(pp[2 * kh + 1][2]), "v"(pp[2 * kh + 1][3]));
    }

    // ---- V fragments (plain b128, same kappa permutation) + PV ----
#pragma unroll
    for (int kh = 0; kh < 2; ++kh)
#pragma unroll
      for (int db = 0; db < 4; ++db) {
        bf16x8 vf = *(const bf16x8*)&Vlds[cur][
            (db * 16 + lr) * 64 + ((4 * kh + lg) ^ (lr & 7)) * 8];
        ov[db] = __builtin_amdgcn_mfma_f32_16x16x32_bf16(
            pk[kh].v, vf, ov[db], 0, 0, 0);
      }
  }

  // ---- epilogue ----
  float invl = 1.0f / lrun;
#pragma unroll
  for (int r = 0; r < 4; ++r) {
    float iv = __shfl(invl, (lane & 48) | (lg * 4 + r));
    size_t row = (size_t)(bb * S_ + qw + lg * 4 + r);
#pragma unroll
    for (int db = 0; db < 4; ++db)
      ctxb[row * 1024 + h * 64 + db * 16 + lr] = f2bf(ov[db][r] * iv);
  }
}

extern "C" void kernel_launch(void* const* d_in, const int* in_sizes, int n_in,
                              void* d_out, int out_size, void* d_ws, size_t ws_size,
                              hipStream_t stream) {
  const float* hs      = (const float*)d_in[0];
  const float* w_qkv   = (const float*)d_in[1];
  const float* b_qkv   = (const float*)d_in[2];
  const float* w_dense = (const float*)d_in[3];
  const float* b_dense = (const float*)d_in[4];
  const float* rtab    = (const float*)d_in[5];
  float* out = (float*)d_out;

  char* ws = (char*)d_ws;
  unsigned short* qkvb = (unsigned short*)ws;                          // 24 MB
  unsigned short* ctxb = (unsigned short*)(ws + (((size_t)24) << 20)); // 8 MB
  unsigned short* hsb  = (unsigned short*)(ws + (((size_t)32) << 20)); // 8 MB
  unsigned short* wqT  = (unsigned short*)(ws + (((size_t)40) << 20)); // 6 MB
  unsigned short* wdT  = (unsigned short*)(ws + (((size_t)46) << 20)); // 2 MB
  unsigned short* vP   = (unsigned short*)(ws + (((size_t)48) << 20)); // 8 MB
  float* biasTab       = (float*)(ws + (((size_t)56) << 20));          // 256 KB

  hipLaunchKernelGGL(bias_table_kernel, dim3(256), dim3(256), 0, stream,
                     rtab, biasTab);
  hipLaunchKernelGGL(cvt_bf16_kernel, dim3(2048), dim3(256), 0, stream,
                     hs, hsb, 4096 * 1024 / 8);
  hipLaunchKernelGGL(transpose_cvt_kernel, dim3(48, 16), dim3(256), 0, stream,
                     w_qkv, wqT, 1024, 3072);
  hipLaunchKernelGGL(transpose_cvt_kernel, dim3(16, 16), dim3(256), 0, stream,
                     w_dense, wdT, 1024, 1024);
  hipLaunchKernelGGL((gemm_mfma_kernel<true>), dim3(24, 32), dim3(256), 0, stream,
                     hsb, wqT, b_qkv, (void*)qkvb, 4096, 3072, 1024);
  hipLaunchKernelGGL(vperm_kernel, dim3(32, 16, 2), dim3(256), 0, stream,
                     qkvb, vP);
  hipLaunchKernelGGL(attn_mfma4_kernel, dim3(512), dim3(512), 0, stream,
                     qkvb, vP, biasTab, ctxb);
  hipLaunchKernelGGL((gemm_mfma_kernel<false>), dim3(8, 32), dim3(256), 0, stream,
                     ctxb, wdT, b_dense, (void*)out, 4096, 1024, 1024);
}